// Round 2
// baseline (3795.325 us; speedup 1.0000x reference)
//
#include <hip/hip_runtime.h>

// LSTM decoder: B=256, H=512, L=2, T=64, O=7
// Persistent-kernel design: one launch runs all 128 layer-steps.
//  - B (weights) for both layers held in registers/AGPRs per wave (loaded once)
//  - A (activations) loaded global->VGPR per MFMA fragment (L2-resident)
//  - c-state in registers across all timesteps
//  - custom device-scope grid barrier between layer-phases (128 barriers)

#define TT 64
#define NO 7

typedef _Float16 h16;
typedef __attribute__((ext_vector_type(8))) _Float16 half8;
typedef __attribute__((ext_vector_type(4))) float f32x4;

__device__ __forceinline__ float sigf(float x)   { return 1.f / (1.f + __expf(-x)); }
__device__ __forceinline__ float tanhf_(float x) { return 1.f - 2.f / (__expf(2.f * x) + 1.f); }

// ---------------- prologue: pack [W_ih | W_hh] -> f16 Wc[l][n][k], k-major ----
__global__ __launch_bounds__(256) void prep_weights(
    const float* __restrict__ Wih, const float* __restrict__ Whh,
    h16* __restrict__ Wc)
{
    size_t gid = (size_t)blockIdx.x * 256 + threadIdx.x;
    size_t base = gid * 8;
    int l = (int)(base >> 21);            // 2048*1024 = 2^21 per layer
    int rem = (int)(base & ((1u << 21) - 1));
    int n = rem >> 10;
    int k = rem & 1023;
    const float* src = (k < 512)
        ? (Wih + ((size_t)l * 2048 + n) * 512 + k)
        : (Whh + ((size_t)l * 2048 + n) * 512 + (k - 512));
    const float4* s4 = (const float4*)src;
    float4 a = s4[0];
    float4 b = s4[1];
    half8 o;
    o[0] = (h16)a.x; o[1] = (h16)a.y; o[2] = (h16)a.z; o[3] = (h16)a.w;
    o[4] = (h16)b.x; o[5] = (h16)b.y; o[6] = (h16)b.z; o[7] = (h16)b.w;
    *(half8*)(Wc + base) = o;
}

// ---------------- prologue: init A-buffers + bias ----------------------------
__global__ __launch_bounds__(256) void init_misc(
    const float* __restrict__ x, const float* __restrict__ h0,
    const float* __restrict__ bih, const float* __restrict__ bhh,
    h16* __restrict__ A0, h16* __restrict__ A1, float* __restrict__ bias)
{
    int i = blockIdx.x * 256 + threadIdx.x;
    if (i < 262144) {              // A0[0][b][k] = [x | h0_layer0]
        int b = i >> 10, k = i & 1023;
        float v = (k < 512) ? x[b * 512 + k] : h0[b * 512 + (k - 512)];
        A0[i] = (h16)v;
        return;
    }
    i -= 262144;
    if (i < 131072) {              // A1[0][b][512+u] = h0_layer1
        int b = i >> 9, u = i & 511;
        A1[b * 1024 + 512 + u] = (h16)h0[131072 + i];
        return;
    }
    i -= 131072;
    if (i < 4096) bias[i] = bih[i] + bhh[i];
}

// ---------------- device-scope grid barrier ----------------------------------
// bar[g*16] for g<8: group counters; bar[128]: root; bar[144]: epoch flag.
__device__ __forceinline__ void grid_barrier(unsigned* bar, unsigned e)
{
    __syncthreads();
    if (threadIdx.x == 0) {
        __threadfence();   // flush our stores to the coherent point
        unsigned g = blockIdx.x & 7;
        unsigned prev = __hip_atomic_fetch_add(&bar[g * 16], 1u,
                            __ATOMIC_ACQ_REL, __HIP_MEMORY_SCOPE_AGENT);
        if (prev == 31) {
            unsigned pr = __hip_atomic_fetch_add(&bar[128], 1u,
                              __ATOMIC_ACQ_REL, __HIP_MEMORY_SCOPE_AGENT);
            if (pr == 7) {
                __hip_atomic_store(&bar[128], 0u, __ATOMIC_RELAXED, __HIP_MEMORY_SCOPE_AGENT);
                for (int i = 0; i < 8; ++i)
                    __hip_atomic_store(&bar[i * 16], 0u, __ATOMIC_RELAXED, __HIP_MEMORY_SCOPE_AGENT);
                __hip_atomic_store(&bar[144], e, __ATOMIC_RELEASE, __HIP_MEMORY_SCOPE_AGENT);
            }
        }
        while (__hip_atomic_load(&bar[144], __ATOMIC_RELAXED, __HIP_MEMORY_SCOPE_AGENT) < e)
            __builtin_amdgcn_s_sleep(1);
        __threadfence();   // invalidate stale L1/L2 before readers proceed
    }
    __syncthreads();
}

// ---------------- the persistent LSTM kernel ---------------------------------
// 256 WGs x 256 thr. WG (r,c): rows 64r..64r+64, h-units 8c..8c+8 (both layers).
// Wave w: rows rowbase..+32 (2 m-tiles), 4 units -> 16 gate-cols (one n-tile,
// col = 4*ulocal + gate). B frags for K=1024, both layers: 64 x half8 in regs.
__global__ __launch_bounds__(256, 1) void lstm_persist(
    const h16* __restrict__ Wc, const float* __restrict__ bias,
    const float* __restrict__ c0in,
    h16* __restrict__ A0, h16* __restrict__ A1,
    float* __restrict__ h1all, float* __restrict__ h_st, float* __restrict__ c_st,
    unsigned* __restrict__ bar)
{
    __shared__ float scr[4][16][16];
    const int wg = blockIdx.x;
    const int r = wg >> 6, c = wg & 63;
    const int w = threadIdx.x >> 6, lane = threadIdx.x & 63;
    const int rowbase = r * 64 + (w >> 1) * 32;
    const int ubase   = c * 8 + (w & 1) * 4;
    const int mcol = lane & 15, kq = lane >> 4;
    const int nrow = (mcol & 3) * 512 + ubase + (mcol >> 2); // weight row for this B col
    const int eunit = ubase + (lane & 3);
    int erow[2]; erow[0] = rowbase + (lane >> 2); erow[1] = rowbase + 16 + (lane >> 2);
    int eoff[2], h1off[2];
    eoff[0] = erow[0] * 1024 + eunit;  eoff[1] = erow[1] * 1024 + eunit;
    h1off[0] = erow[0] * 512 + eunit;  h1off[1] = erow[1] * 512 + eunit;
    const int srow = (rowbase + mcol) * 1024 + kq * 8;  // A-frag base (elements)
    float (*scrw)[16] = scr[w];

    // ---- load B fragments for both layers (permanent registers/AGPRs) ----
    half8 Bw0[32], Bw1[32];
#pragma unroll
    for (int ks = 0; ks < 32; ++ks) {
        Bw0[ks] = *(const half8*)(Wc + (size_t)nrow * 1024 + ks * 32 + kq * 8);
        Bw1[ks] = *(const half8*)(Wc + (size_t)(2048 + nrow) * 1024 + ks * 32 + kq * 8);
    }

    // ---- biases (i,f,g,o) per layer for this lane's unit ----
    float4 bz0 = make_float4(bias[eunit], bias[512 + eunit],
                             bias[1024 + eunit], bias[1536 + eunit]);
    float4 bz1 = make_float4(bias[2048 + eunit], bias[2048 + 512 + eunit],
                             bias[2048 + 1024 + eunit], bias[2048 + 1536 + eunit]);

    // ---- c-state in registers ----
    float creg[2][2], hreg[2][2];
#pragma unroll
    for (int mt = 0; mt < 2; ++mt) {
        creg[0][mt] = c0in[erow[mt] * 512 + eunit];
        creg[1][mt] = c0in[131072 + erow[mt] * 512 + eunit];
        hreg[0][mt] = 0.f; hreg[1][mt] = 0.f;
    }

#define PHASE(SRC, BW, BZ, CREG, HREG, DSTX, DSTH, H1DST, DO_H1)              \
  do {                                                                        \
    f32x4 acc0 = {0.f, 0.f, 0.f, 0.f}, acc1 = {0.f, 0.f, 0.f, 0.f};           \
    const h16* ap = (SRC) + srow;                                             \
    _Pragma("unroll")                                                         \
    for (int ks = 0; ks < 32; ++ks) {                                         \
      half8 a0 = *(const half8*)(ap + ks * 32);                               \
      half8 a1 = *(const half8*)(ap + 16 * 1024 + ks * 32);                   \
      acc0 = __builtin_amdgcn_mfma_f32_16x16x32_f16(a0, BW[ks], acc0, 0, 0, 0); \
      acc1 = __builtin_amdgcn_mfma_f32_16x16x32_f16(a1, BW[ks], acc1, 0, 0, 0); \
    }                                                                         \
    _Pragma("unroll")                                                         \
    for (int mt = 0; mt < 2; ++mt) {                                          \
      f32x4 accv = mt ? acc1 : acc0;                                          \
      _Pragma("unroll")                                                       \
      for (int rr = 0; rr < 4; ++rr) scrw[(lane >> 4) * 4 + rr][mcol] = accv[rr]; \
      float4 g4 = *(const float4*)&scrw[lane >> 2][(lane & 3) * 4];           \
      float iv = sigf(g4.x + (BZ).x);                                         \
      float fv = sigf(g4.y + (BZ).y);                                         \
      float gv = tanhf_(g4.z + (BZ).z);                                       \
      float ov = sigf(g4.w + (BZ).w);                                         \
      float cc = fv * (CREG)[mt] + iv * gv;                                   \
      float hh = ov * tanhf_(cc);                                             \
      (CREG)[mt] = cc; (HREG)[mt] = hh;                                       \
      h16 hv = (h16)hh;                                                       \
      (DSTX)[eoff[mt]] = hv;                                                  \
      (DSTH)[eoff[mt] + 512] = hv;                                            \
      if (DO_H1) (H1DST)[h1off[mt]] = hh;                                     \
    }                                                                         \
  } while (0)

    const int AS = 262144;   // halfs per A parity buffer
    unsigned e = 0;
    for (int t = 0; t < TT; ++t) {
        const int p = t & 1, q = p ^ 1;
        // layer 0: reads A0[p]; h0(t) -> A1[p].x, A0[q].h
        PHASE(A0 + (size_t)p * AS, Bw0, bz0, creg[0], hreg[0],
              A1 + (size_t)p * AS, A0 + (size_t)q * AS, h1all, 0);
        grid_barrier(bar, ++e);
        // layer 1: reads A1[p]; h1(t) -> A0[q].x, A1[q].h, h1all[t]
        PHASE(A1 + (size_t)p * AS, Bw1, bz1, creg[1], hreg[1],
              A0 + (size_t)q * AS, A1 + (size_t)q * AS, h1all + (size_t)t * 131072, 1);
        grid_barrier(bar, ++e);
    }

    // ---- final hT / cT ----
#pragma unroll
    for (int mt = 0; mt < 2; ++mt) {
        h_st[h1off[mt]]           = hreg[0][mt];
        h_st[131072 + h1off[mt]]  = hreg[1][mt];
        c_st[h1off[mt]]           = creg[0][mt];
        c_st[131072 + h1off[mt]]  = creg[1][mt];
    }
#undef PHASE
}

// ---------------- final FC over all stored h1(t): (T*B) x 7, K=512 -----------
__global__ __launch_bounds__(256) void fc_kernel(
    const float* __restrict__ h1all, const float* __restrict__ Wfc,
    const float* __restrict__ bfc, float* __restrict__ out)
{
    __shared__ float wl[NO * 512];
    for (int i = threadIdx.x; i < NO * 512; i += 256) wl[i] = Wfc[i];
    __syncthreads();
    const int wave = threadIdx.x >> 6, lane = threadIdx.x & 63;
    const int row = blockIdx.x * 4 + wave;   // row = t*256 + b
    const float* hr = h1all + (size_t)row * 512;
    float acc[NO] = {0, 0, 0, 0, 0, 0, 0};
#pragma unroll
    for (int i = 0; i < 8; ++i) {
        float hv = hr[i * 64 + lane];
#pragma unroll
        for (int o = 0; o < NO; ++o) acc[o] += hv * wl[o * 512 + i * 64 + lane];
    }
#pragma unroll
    for (int o = 0; o < NO; ++o)
#pragma unroll
        for (int off = 32; off; off >>= 1) acc[o] += __shfl_down(acc[o], off);
    if (lane == 0) {
        const int t = row >> 8, b = row & 255;
#pragma unroll
        for (int o = 0; o < NO; ++o) out[b * (TT * NO) + t * NO + o] = acc[o] + bfc[o];
    }
}

extern "C" void kernel_launch(void* const* d_in, const int* in_sizes, int n_in,
                              void* d_out, int out_size, void* d_ws, size_t ws_size,
                              hipStream_t stream)
{
    (void)in_sizes; (void)n_in; (void)out_size; (void)ws_size;
    const float* x   = (const float*)d_in[0];
    const float* h0  = (const float*)d_in[1];
    const float* c0  = (const float*)d_in[2];
    const float* Wih = (const float*)d_in[3];
    const float* Whh = (const float*)d_in[4];
    const float* bih = (const float*)d_in[5];
    const float* bhh = (const float*)d_in[6];
    const float* Wfc = (const float*)d_in[7];
    const float* bfc = (const float*)d_in[8];

    float* outf = (float*)d_out;                 // decoded (256*64*7)
    float* h_st = outf + 114688;                 // hT (2,256,512)
    float* c_st = h_st + 262144;                 // cT (2,256,512)

    char* ws = (char*)d_ws;
    h16*      Wc    = (h16*)ws;                          // 8 MB
    float*    bias  = (float*)(ws + 8388608);            // 16 KB
    h16*      A0    = (h16*)(ws + 8404992);              // 1 MB (2 parity bufs)
    h16*      A1    = (h16*)(ws + 9453568);              // 1 MB
    float*    h1all = (float*)(ws + 10502144);           // 32 MB
    unsigned* bar   = (unsigned*)(ws + 44056576);        // 1 KB

    prep_weights<<<2048, 256, 0, stream>>>(Wih, Whh, Wc);
    init_misc<<<1552, 256, 0, stream>>>(x, h0, bih, bhh, A0, A1, bias);
    hipMemsetAsync(bar, 0, 1024, stream);
    lstm_persist<<<256, 256, 0, stream>>>(Wc, bias, c0, A0, A1,
                                          h1all, h_st, c_st, bar);
    fc_kernel<<<4096, 256, 0, stream>>>(h1all, Wfc, bfc, outf);
}

// Round 3
// 1750.085 us; speedup vs baseline: 2.1687x; 2.1687x over previous
//
#include <hip/hip_runtime.h>

// LSTM decoder: B=256, H=512, L=2, T=64, O=7
// Multi-launch (graph-replayed) design: one fused GEMM+cell kernel per
// layer-step (128 total), 256 WGs each, double-buffered global_load_lds
// staging, fp16 MFMA 16x16x32 with fp32 accumulate.

#define TT 64
#define NO 7

typedef _Float16 h16;
typedef __attribute__((ext_vector_type(8))) _Float16 half8;
typedef __attribute__((ext_vector_type(4))) float f32x4;

__device__ __forceinline__ float sigf(float x)   { return 1.f / (1.f + __expf(-x)); }
__device__ __forceinline__ float tanhf_(float x) { return 1.f - 2.f / (__expf(2.f * x) + 1.f); }

__device__ __forceinline__ void gl2lds16(const h16* g, const h16* l)
{
    __builtin_amdgcn_global_load_lds(
        (const __attribute__((address_space(1))) void*)g,
        (__attribute__((address_space(3))) void*)l, 16, 0, 0);
}

// ---------------- prologue: pack [W_ih | W_hh] -> f16 Wc[l][n][k], k-major ----
__global__ __launch_bounds__(256) void prep_weights(
    const float* __restrict__ Wih, const float* __restrict__ Whh,
    h16* __restrict__ Wc)
{
    size_t gid = (size_t)blockIdx.x * 256 + threadIdx.x;
    size_t base = gid * 8;
    int l = (int)(base >> 21);            // 2048*1024 = 2^21 per layer
    int rem = (int)(base & ((1u << 21) - 1));
    int n = rem >> 10;
    int k = rem & 1023;
    const float* src = (k < 512)
        ? (Wih + ((size_t)l * 2048 + n) * 512 + k)
        : (Whh + ((size_t)l * 2048 + n) * 512 + (k - 512));
    const float4* s4 = (const float4*)src;
    float4 a = s4[0];
    float4 b = s4[1];
    half8 o;
    o[0] = (h16)a.x; o[1] = (h16)a.y; o[2] = (h16)a.z; o[3] = (h16)a.w;
    o[4] = (h16)b.x; o[5] = (h16)b.y; o[6] = (h16)b.z; o[7] = (h16)b.w;
    *(half8*)(Wc + base) = o;
}

// ---------------- prologue: init A-buffers, h/c state, bias ------------------
__global__ __launch_bounds__(256) void init_misc(
    const float* __restrict__ x, const float* __restrict__ h0,
    const float* __restrict__ c0, const float* __restrict__ bih,
    const float* __restrict__ bhh,
    h16* __restrict__ A0, h16* __restrict__ A1,
    float* __restrict__ h_st, float* __restrict__ c_st,
    float* __restrict__ bias)
{
    int i = blockIdx.x * 256 + threadIdx.x;
    if (i < 262144) {              // A0[0][b][k] = [x | h0_layer0]
        int b = i >> 10, k = i & 1023;
        float v = (k < 512) ? x[b * 512 + k] : h0[b * 512 + (k - 512)];
        A0[i] = (h16)v;
        return;
    }
    i -= 262144;
    if (i < 131072) {              // A1[0][b][512+u] = h0_layer1
        int b = i >> 9, u = i & 511;
        A1[b * 1024 + 512 + u] = (h16)h0[131072 + i];
        return;
    }
    i -= 131072;
    if (i < 262144) { h_st[i] = h0[i]; return; }
    i -= 262144;
    if (i < 262144) { c_st[i] = c0[i]; return; }
    i -= 262144;
    if (i < 4096) bias[i] = bih[i] + bhh[i];
}

// ---------------- fused GEMM + LSTM cell for one layer-step ------------------
// grid (64, 4): bx = unit-slice (8 h-units -> 32 gate-cols), by = 64-row tile.
// Wave w: rows (w>>1)*32..+32 (2 m-tiles), units (w&1)*4..+4 (1 n-tile of 16
// gate-cols, col = 4*ulocal + gate). K=1024 streamed in 8 dbuf chunks of 128.
__global__ __launch_bounds__(256) void lstm_step(
    const h16* __restrict__ A, const h16* __restrict__ W,
    const float* __restrict__ bias,
    float* __restrict__ c_st, float* __restrict__ h_st,
    h16* __restrict__ dst1, int off1,
    h16* __restrict__ dst2, int off2,
    h16* __restrict__ h1f)
{
    __shared__ h16 Abuf[2][64 * 128];   // [chunk parity][row][k] 16 KB each
    __shared__ h16 Bbuf[2][32 * 128];   // [parity][gate-col row][k] 8 KB each
    __shared__ float scr[4][16][16];    // per-wave epilogue transpose

    const int tid  = threadIdx.x;
    const int w    = tid >> 6, lane = tid & 63;
    const int u0   = blockIdx.x * 8;
    const int m0   = blockIdx.y * 64;
    const int rowbase = m0 + (w >> 1) * 32;
    const int ubase   = u0 + (w & 1) * 4;
    const int mcol = lane & 15, kq = lane >> 4;

    // staging address precompute: A e = tid + 256*i (i<4); B e = tid + 256*i (i<2)
    const h16* Ag[4]; const h16* Bg[2];
    const h16* Al[4]; const h16* Bl[2];
#pragma unroll
    for (int i = 0; i < 4; ++i) {
        int e = tid + 256 * i, arow = e >> 4, k8 = (e & 15) * 8;
        Ag[i] = A + (size_t)(m0 + arow) * 1024 + k8;
        Al[i] = &Abuf[0][e * 8];
    }
#pragma unroll
    for (int i = 0; i < 2; ++i) {
        int e = tid + 256 * i, br = e >> 4, k8 = (e & 15) * 8;
        int uh = br >> 4, bc = br & 15;
        int wrow = (bc & 3) * 512 + (u0 + uh * 4) + (bc >> 2);
        Bg[i] = W + (size_t)wrow * 1024 + k8;
        Bl[i] = &Bbuf[0][e * 8];
    }
    const int APAR = 64 * 128, BPAR = 32 * 128;  // parity strides (halfs)

#define STAGE(K0, PB) do {                                                    \
    _Pragma("unroll")                                                         \
    for (int i = 0; i < 4; ++i) gl2lds16(Ag[i] + (K0), Al[i] + (PB) * APAR);  \
    _Pragma("unroll")                                                         \
    for (int i = 0; i < 2; ++i) gl2lds16(Bg[i] + (K0), Bl[i] + (PB) * BPAR);  \
} while (0)

    f32x4 acc0 = {0.f, 0.f, 0.f, 0.f}, acc1 = {0.f, 0.f, 0.f, 0.f};
    const int aoff0 = ((w >> 1) * 32 + mcol) * 128 + kq * 8;
    const int aoff1 = aoff0 + 16 * 128;
    const int boff  = ((w & 1) * 16 + mcol) * 128 + kq * 8;

    STAGE(0, 0);
    __syncthreads();
#pragma unroll
    for (int kt = 0; kt < 8; ++kt) {
        const int pb = kt & 1;
        if (kt < 7) STAGE((kt + 1) * 128, pb ^ 1);   // prefetch next chunk
#pragma unroll
        for (int ks = 0; ks < 4; ++ks) {
            half8 b  = *(const half8*)&Bbuf[pb][boff  + ks * 32];
            half8 a0 = *(const half8*)&Abuf[pb][aoff0 + ks * 32];
            half8 a1 = *(const half8*)&Abuf[pb][aoff1 + ks * 32];
            acc0 = __builtin_amdgcn_mfma_f32_16x16x32_f16(a0, b, acc0, 0, 0, 0);
            acc1 = __builtin_amdgcn_mfma_f32_16x16x32_f16(a1, b, acc1, 0, 0, 0);
        }
        __syncthreads();   // drains prefetch (overlapped with the 8 MFMAs above)
    }
#undef STAGE

    // epilogue: per-wave transpose so each lane holds i/f/g/o of one unit
    const int eunit = ubase + (lane & 3);
    const int er0   = rowbase + (lane >> 2);
    float4 bz = make_float4(bias[eunit], bias[512 + eunit],
                            bias[1024 + eunit], bias[1536 + eunit]);
    float (*scrw)[16] = scr[w];
#pragma unroll
    for (int mt = 0; mt < 2; ++mt) {
        f32x4 accv = mt ? acc1 : acc0;
#pragma unroll
        for (int rr = 0; rr < 4; ++rr) scrw[kq * 4 + rr][mcol] = accv[rr];
        float4 g4 = *(const float4*)&scrw[lane >> 2][(lane & 3) * 4];
        float iv = sigf(g4.x + bz.x);
        float fv = sigf(g4.y + bz.y);
        float gv = tanhf_(g4.z + bz.z);
        float ov = sigf(g4.w + bz.w);
        const int erow = er0 + mt * 16;
        float cc = fv * c_st[erow * 512 + eunit] + iv * gv;
        float hh = ov * tanhf_(cc);
        c_st[erow * 512 + eunit] = cc;
        h_st[erow * 512 + eunit] = hh;
        h16 hv = (h16)hh;
        dst1[(size_t)erow * 1024 + off1 + eunit] = hv;
        dst2[(size_t)erow * 1024 + off2 + eunit] = hv;
        if (h1f) h1f[erow * 512 + eunit] = hv;
    }
}

// ---------------- final FC over all stored h1(t): (T*B) x 7, K=512 -----------
__global__ __launch_bounds__(256) void fc_kernel(
    const h16* __restrict__ h1f, const float* __restrict__ Wfc,
    const float* __restrict__ bfc, float* __restrict__ out)
{
    __shared__ float wl[NO * 512];
    for (int i = threadIdx.x; i < NO * 512; i += 256) wl[i] = Wfc[i];
    __syncthreads();
    const int wave = threadIdx.x >> 6, lane = threadIdx.x & 63;
    const int row = blockIdx.x * 4 + wave;   // row = t*256 + b
    const h16* hr = h1f + (size_t)row * 512;
    float acc[NO] = {0, 0, 0, 0, 0, 0, 0};
#pragma unroll
    for (int i = 0; i < 8; ++i) {
        float hv = (float)hr[i * 64 + lane];
#pragma unroll
        for (int o = 0; o < NO; ++o) acc[o] += hv * wl[o * 512 + i * 64 + lane];
    }
#pragma unroll
    for (int o = 0; o < NO; ++o)
#pragma unroll
        for (int off = 32; off; off >>= 1) acc[o] += __shfl_down(acc[o], off);
    if (lane == 0) {
        const int t = row >> 8, b = row & 255;
#pragma unroll
        for (int o = 0; o < NO; ++o) out[b * (TT * NO) + t * NO + o] = acc[o] + bfc[o];
    }
}

extern "C" void kernel_launch(void* const* d_in, const int* in_sizes, int n_in,
                              void* d_out, int out_size, void* d_ws, size_t ws_size,
                              hipStream_t stream)
{
    (void)in_sizes; (void)n_in; (void)out_size; (void)ws_size;
    const float* x   = (const float*)d_in[0];
    const float* h0  = (const float*)d_in[1];
    const float* c0  = (const float*)d_in[2];
    const float* Wih = (const float*)d_in[3];
    const float* Whh = (const float*)d_in[4];
    const float* bih = (const float*)d_in[5];
    const float* bhh = (const float*)d_in[6];
    const float* Wfc = (const float*)d_in[7];
    const float* bfc = (const float*)d_in[8];

    float* outf = (float*)d_out;                 // decoded (256*64*7)
    float* h_st = outf + 114688;                 // hT (2,256,512)
    float* c_st = h_st + 262144;                 // cT (2,256,512)

    char* ws = (char*)d_ws;
    h16*   Wc   = (h16*)ws;                          // 8 MB
    float* bias = (float*)(ws + 8388608);            // 16 KB
    h16*   A0   = (h16*)(ws + 8404992);              // 1 MB (2 parity bufs)
    h16*   A1   = (h16*)(ws + 9453568);              // 1 MB
    h16*   h1f  = (h16*)(ws + 10502144);             // 16 MB (T x B x H f16)

    prep_weights<<<2048, 256, 0, stream>>>(Wih, Whh, Wc);
    init_misc<<<3600, 256, 0, stream>>>(x, h0, c0, bih, bhh, A0, A1, h_st, c_st, bias);

    const int AS = 262144;    // halfs per A parity buffer
    const int WS = 2097152;   // halfs per layer weight block
    const int CS = 131072;    // floats per layer state block
    for (int t = 0; t < TT; ++t) {
        int p = t & 1, q = p ^ 1;
        // layer 0: reads A0[p]; h0(t) -> A1[p].x, A0[q].h
        lstm_step<<<dim3(64, 4), 256, 0, stream>>>(
            A0 + (size_t)p * AS, Wc, bias, c_st, h_st,
            A1 + (size_t)p * AS, 0, A0 + (size_t)q * AS, 512, (h16*)nullptr);
        // layer 1: reads A1[p]; h1(t) -> A0[q].x, A1[q].h, h1f[t]
        lstm_step<<<dim3(64, 4), 256, 0, stream>>>(
            A1 + (size_t)p * AS, Wc + WS, bias + 2048, c_st + CS, h_st + CS,
            A0 + (size_t)q * AS, 0, A1 + (size_t)q * AS, 512,
            h1f + (size_t)t * 131072);
    }
    fc_kernel<<<4096, 256, 0, stream>>>(h1f, Wfc, bfc, outf);
}

// Round 5
// 1033.455 us; speedup vs baseline: 3.6725x; 1.6934x over previous
//
#include <hip/hip_runtime.h>

// LSTM decoder: B=256, H=512, L=2, T=64, O=7
// Persistent kernel:
//  - Cross-WG h-activations move via sc0sc1 (L2-bypass, IC-coherent)
//    loads/stores in inline asm. No fences, no acquire-release.
//  - Sync: per-(phase, m-tile) counters; signal = relaxed fetch_add(1),
//    poll = relaxed fetch_add(0) (RMW executes at IC => never stale).
//  - Weights in AGPRs per wave (loaded once), c-state in VGPRs all 64 steps,
//    A staged to 64KB LDS (2-chunk double buffer, XOR bank swizzle).
// R4 bug fixed: K-chunk byte offset is c*512 (256 halfs/row/chunk), was c*1024.

#define TT 64
#define NO 7

typedef _Float16 h16;
typedef __attribute__((ext_vector_type(8))) _Float16 half8;
typedef __attribute__((ext_vector_type(4))) float f32x4;
typedef __attribute__((ext_vector_type(4))) int i32x4;

__device__ __forceinline__ float sigf(float x)   { return 1.f / (1.f + __expf(-x)); }
__device__ __forceinline__ float tanhf_(float x) { return 1.f - 2.f / (__expf(2.f * x) + 1.f); }

// ---------------- prologue: pack [W_ih | W_hh] -> f16 Wc[l][n][k], k-major ----
__global__ __launch_bounds__(256) void prep_weights(
    const float* __restrict__ Wih, const float* __restrict__ Whh,
    h16* __restrict__ Wc)
{
    size_t gid = (size_t)blockIdx.x * 256 + threadIdx.x;
    size_t base = gid * 8;
    int l = (int)(base >> 21);
    int rem = (int)(base & ((1u << 21) - 1));
    int n = rem >> 10;
    int k = rem & 1023;
    const float* src = (k < 512)
        ? (Wih + ((size_t)l * 2048 + n) * 512 + k)
        : (Whh + ((size_t)l * 2048 + n) * 512 + (k - 512));
    const float4* s4 = (const float4*)src;
    float4 a = s4[0];
    float4 b = s4[1];
    half8 o;
    o[0] = (h16)a.x; o[1] = (h16)a.y; o[2] = (h16)a.z; o[3] = (h16)a.w;
    o[4] = (h16)b.x; o[5] = (h16)b.y; o[6] = (h16)b.z; o[7] = (h16)b.w;
    *(half8*)(Wc + base) = o;
}

// ---------------- prologue: init A-buffers + bias ----------------------------
__global__ __launch_bounds__(256) void init_misc(
    const float* __restrict__ x, const float* __restrict__ h0,
    const float* __restrict__ bih, const float* __restrict__ bhh,
    h16* __restrict__ A0, h16* __restrict__ A1, float* __restrict__ bias)
{
    int i = blockIdx.x * 256 + threadIdx.x;
    if (i < 262144) {              // A0[0][b][k] = [x | h0_layer0]
        int b = i >> 10, k = i & 1023;
        float v = (k < 512) ? x[b * 512 + k] : h0[b * 512 + (k - 512)];
        A0[i] = (h16)v;
        return;
    }
    i -= 262144;
    if (i < 131072) {              // A1[0][b][512+u] = h0_layer1
        int b = i >> 9, u = i & 511;
        A1[b * 1024 + 512 + u] = (h16)h0[131072 + i];
        return;
    }
    i -= 131072;
    if (i < 4096) bias[i] = bih[i] + bhh[i];
}

// ---------------- persistent LSTM ------------------------------------------
// 256 WGs x 256 thr, 1 WG/CU. WG = (m = wg>>6 : 64-row tile, us = wg&63 :
// 8 h-units). Wave w: rows (w>>1)*32..+32 (2 m-subtiles), units (w&1)*4..+4
// (16 gate-cols, col = 4*ulocal + gate).
__global__ __launch_bounds__(256, 1) void lstm_persist(
    const h16* __restrict__ Wc, const float* __restrict__ bias,
    const float* __restrict__ c0in,
    h16* __restrict__ A0, h16* __restrict__ A1,
    h16* __restrict__ h1f, float* __restrict__ h_st, float* __restrict__ c_st,
    unsigned* __restrict__ flags)
{
    __shared__ char ldsraw[65536];   // 2 x 32KB A-chunk double buffer

    const int wg   = blockIdx.x;
    const int m    = wg >> 6, us = wg & 63;
    const int tid  = threadIdx.x, w = tid >> 6, lane = tid & 63;
    const int u0   = us * 8;
    const int m0   = m * 64;
    const int rowbase = m0 + (w >> 1) * 32;
    const int ubase   = u0 + (w & 1) * 4;
    const int mcol = lane & 15, kq = lane >> 4;
    const int nrow = (mcol & 3) * 512 + ubase + (mcol >> 2);
    const int lrow = (w >> 1) * 32 + mcol;     // local row of m-subtile 0
    const int sw   = mcol & 7;                 // LDS XOR swizzle key

    // ---- B fragments for both layers -> registers/AGPRs (loaded once) ----
    half8 Bw0[32], Bw1[32];
#pragma unroll
    for (int ks = 0; ks < 32; ++ks) {
        Bw0[ks] = *(const half8*)(Wc + (size_t)nrow * 1024 + ks * 32 + kq * 8);
        Bw1[ks] = *(const half8*)(Wc + (size_t)(2048 + nrow) * 1024 + ks * 32 + kq * 8);
    }

    // ---- epilogue lane mapping (round-2 verified) ----
    const int eunit = ubase + (lane & 3);
    const int erow0 = rowbase + (lane >> 2);   // m-subtile 0; +16 for subtile 1
    float4 bz0 = make_float4(bias[eunit], bias[512 + eunit],
                             bias[1024 + eunit], bias[1536 + eunit]);
    float4 bz1 = make_float4(bias[2048 + eunit], bias[2048 + 512 + eunit],
                             bias[2048 + 1024 + eunit], bias[2048 + 1536 + eunit]);

    float creg[2][2], hreg[2][2];
#pragma unroll
    for (int mt = 0; mt < 2; ++mt) {
        creg[0][mt] = c0in[(erow0 + mt * 16) * 512 + eunit];
        creg[1][mt] = c0in[131072 + (erow0 + mt * 16) * 512 + eunit];
        hreg[0][mt] = 0.f; hreg[1][mt] = 0.f;
    }

// issue 8 x 16B sc0sc1 (L2-bypass) loads of K-chunk c of this WG's 64xK tile
// chunk c covers k-halfs [c*256, c*256+256) of each row: 512 B/row/chunk
#define ISSUE_CHUNK(GB, c) do {                                               \
    _Pragma("unroll")                                                         \
    for (int j = 0; j < 8; ++j) {                                             \
        int g = j * 256 + tid;                                                \
        int voff = (g >> 5) * 2048 + (c) * 512 + (g & 31) * 16;               \
        asm volatile("global_load_dwordx4 %0, %1, %2 sc0 sc1"                 \
            : "=v"(tmp[j]) : "v"(voff), "s"(GB) : "memory");                  \
    } } while (0)

// drain them oldest-first into LDS buffer `par` with XOR swizzle
#define WRITE_CHUNK(par) do {                                                 \
    _Pragma("unroll")                                                         \
    for (int j = 0; j < 8; ++j) {                                             \
        asm volatile("s_waitcnt vmcnt(%0)" :: "i"(7 - j) : "memory");         \
        int g = j * 256 + tid;                                                \
        int row = g >> 5, bc = g & 31;                                        \
        *(i32x4*)(ldsraw + (par) * 32768 + row * 512 +                        \
                  ((bc ^ (row & 7)) * 16)) = tmp[j];                          \
    } } while (0)

#define PHASE(PH, WAIT, GSRC, BW, BZ, CREG, HREG, DSTX, DSTH, H1, DO_H1) do { \
    if ((WAIT) && tid == 0) {                                                 \
        unsigned* fl = flags + ((PH) - 1) * 64 + m * 16;                      \
        while (__hip_atomic_fetch_add(fl, 0u, __ATOMIC_RELAXED,               \
                   __HIP_MEMORY_SCOPE_AGENT) < 64u)                           \
            __builtin_amdgcn_s_sleep(1);                                      \
    }                                                                         \
    __syncthreads();                                                          \
    const char* gb = (const char*)(GSRC) + (size_t)m0 * 2048;                 \
    i32x4 tmp[8];                                                             \
    ISSUE_CHUNK(gb, 0);                                                       \
    WRITE_CHUNK(0);                                                           \
    f32x4 acc0 = {0.f,0.f,0.f,0.f}, acc1 = {0.f,0.f,0.f,0.f};                 \
    _Pragma("unroll")                                                         \
    for (int ch = 0; ch < 4; ++ch) {                                          \
        __syncthreads();                                                      \
        if (ch < 3) ISSUE_CHUNK(gb, ch + 1);                                  \
        const int par = ch & 1;                                               \
        _Pragma("unroll")                                                     \
        for (int ks = 0; ks < 8; ++ks) {                                      \
            half8 a0 = *(const half8*)(ldsraw + par * 32768 + lrow * 512 +    \
                          (((kq + 4 * ks) ^ sw) * 16));                       \
            half8 a1 = *(const half8*)(ldsraw + par * 32768 +                 \
                          (lrow + 16) * 512 + (((kq + 4 * ks) ^ sw) * 16));   \
            acc0 = __builtin_amdgcn_mfma_f32_16x16x32_f16(a0, (BW)[ch*8+ks],  \
                                                          acc0, 0, 0, 0);     \
            acc1 = __builtin_amdgcn_mfma_f32_16x16x32_f16(a1, (BW)[ch*8+ks],  \
                                                          acc1, 0, 0, 0);     \
        }                                                                     \
        if (ch < 3) WRITE_CHUNK(par ^ 1);                                     \
    }                                                                         \
    __syncthreads();                                                          \
    float* scrw = (float*)(ldsraw + w * 1024);  /* 16x16 f32, per wave */     \
    _Pragma("unroll")                                                         \
    for (int mt = 0; mt < 2; ++mt) {                                          \
        f32x4 accv = mt ? acc1 : acc0;                                        \
        _Pragma("unroll")                                                     \
        for (int rr = 0; rr < 4; ++rr)                                        \
            scrw[(kq * 4 + rr) * 16 + mcol] = accv[rr];                       \
        float4 g4 = *(const float4*)&scrw[(lane >> 2) * 16 + (lane & 3) * 4]; \
        float iv = sigf(g4.x + (BZ).x);                                       \
        float fv = sigf(g4.y + (BZ).y);                                       \
        float gv = tanhf_(g4.z + (BZ).z);                                     \
        float ov = sigf(g4.w + (BZ).w);                                       \
        float cc = fv * (CREG)[mt] + iv * gv;                                 \
        float hh = ov * tanhf_(cc);                                           \
        (CREG)[mt] = cc; (HREG)[mt] = hh;                                     \
        h16 hv = (h16)hh;                                                     \
        unsigned hb = (unsigned)__builtin_bit_cast(unsigned short, hv);       \
        int vx = ((erow0 + mt * 16) * 1024 + eunit) * 2;                      \
        asm volatile("global_store_short %0, %1, %2 sc0 sc1"                  \
            :: "v"(vx), "v"(hb), "s"(DSTX) : "memory");                       \
        asm volatile("global_store_short %0, %1, %2 sc0 sc1"                  \
            :: "v"(vx + 1024), "v"(hb), "s"(DSTH) : "memory");                \
        if (DO_H1) (H1)[(erow0 + mt * 16) * 512 + eunit] = hv;                \
    }                                                                         \
    asm volatile("s_waitcnt vmcnt(0)" ::: "memory");                          \
    __syncthreads();                                                          \
    if (tid == 0)                                                             \
        __hip_atomic_fetch_add(flags + (PH) * 64 + m * 16, 1u,                \
                               __ATOMIC_RELAXED, __HIP_MEMORY_SCOPE_AGENT);   \
} while (0)

    const int AS = 262144;   // halfs per A parity buffer
#pragma unroll 1
    for (int t = 0; t < TT; ++t) {
        const int p = t & 1, q = p ^ 1;
        // layer 0 (phase 2t): reads A0[p]; h0(t) -> A1[p].x, A0[q].h
        PHASE(2 * t, t > 0, A0 + (size_t)p * AS, Bw0, bz0, creg[0], hreg[0],
              (A1 + (size_t)p * AS), (A0 + (size_t)q * AS), h1f, 0);
        // layer 1 (phase 2t+1): reads A1[p]; h1(t) -> A0[q].x, A1[q].h, h1f[t]
        PHASE(2 * t + 1, 1, A1 + (size_t)p * AS, Bw1, bz1, creg[1], hreg[1],
              (A0 + (size_t)q * AS), (A1 + (size_t)q * AS),
              (h1f + (size_t)t * 131072), 1);
    }

    // ---- final hT / cT (normal stores; kernel-end release flushes) ----
#pragma unroll
    for (int mt = 0; mt < 2; ++mt) {
        int idx = (erow0 + mt * 16) * 512 + eunit;
        h_st[idx]          = hreg[0][mt];
        h_st[131072 + idx] = hreg[1][mt];
        c_st[idx]          = creg[0][mt];
        c_st[131072 + idx] = creg[1][mt];
    }
}

// ---------------- final FC over all stored h1(t): (T*B) x 7, K=512 -----------
__global__ __launch_bounds__(256) void fc_kernel(
    const h16* __restrict__ h1f, const float* __restrict__ Wfc,
    const float* __restrict__ bfc, float* __restrict__ out)
{
    __shared__ float wl[NO * 512];
    for (int i = threadIdx.x; i < NO * 512; i += 256) wl[i] = Wfc[i];
    __syncthreads();
    const int wave = threadIdx.x >> 6, lane = threadIdx.x & 63;
    const int row = blockIdx.x * 4 + wave;   // row = t*256 + b
    const h16* hr = h1f + (size_t)row * 512;
    float acc[NO] = {0, 0, 0, 0, 0, 0, 0};
#pragma unroll
    for (int i = 0; i < 8; ++i) {
        float hv = (float)hr[i * 64 + lane];
#pragma unroll
        for (int o = 0; o < NO; ++o) acc[o] += hv * wl[o * 512 + i * 64 + lane];
    }
#pragma unroll
    for (int o = 0; o < NO; ++o)
#pragma unroll
        for (int off = 32; off; off >>= 1) acc[o] += __shfl_down(acc[o], off);
    if (lane == 0) {
        const int t = row >> 8, b = row & 255;
#pragma unroll
        for (int o = 0; o < NO; ++o) out[b * (TT * NO) + t * NO + o] = acc[o] + bfc[o];
    }
}

extern "C" void kernel_launch(void* const* d_in, const int* in_sizes, int n_in,
                              void* d_out, int out_size, void* d_ws, size_t ws_size,
                              hipStream_t stream)
{
    (void)in_sizes; (void)n_in; (void)out_size; (void)ws_size;
    const float* x   = (const float*)d_in[0];
    const float* h0  = (const float*)d_in[1];
    const float* c0  = (const float*)d_in[2];
    const float* Wih = (const float*)d_in[3];
    const float* Whh = (const float*)d_in[4];
    const float* bih = (const float*)d_in[5];
    const float* bhh = (const float*)d_in[6];
    const float* Wfc = (const float*)d_in[7];
    const float* bfc = (const float*)d_in[8];

    float* outf = (float*)d_out;                 // decoded (256*64*7)
    float* h_st = outf + 114688;                 // hT (2,256,512)
    float* c_st = h_st + 262144;                 // cT (2,256,512)

    char* ws = (char*)d_ws;
    h16*      Wc    = (h16*)ws;                          // 8 MB
    float*    bias  = (float*)(ws + 8388608);            // 16 KB
    h16*      A0    = (h16*)(ws + 8404992);              // 1 MB (2 parity bufs)
    h16*      A1    = (h16*)(ws + 9453568);              // 1 MB
    h16*      h1f   = (h16*)(ws + 10502144);             // 16 MB (T x B x H f16)
    unsigned* flags = (unsigned*)(ws + 27279360);        // 32 KB (128 ph x 4 m)

    prep_weights<<<2048, 256, 0, stream>>>(Wih, Whh, Wc);
    init_misc<<<1552, 256, 0, stream>>>(x, h0, bih, bhh, A0, A1, bias);
    hipMemsetAsync(flags, 0, 32768, stream);
    lstm_persist<<<256, 256, 0, stream>>>(Wc, bias, c0, A0, A1,
                                          h1f, h_st, c_st, flags);
    fc_kernel<<<4096, 256, 0, stream>>>(h1f, Wfc, bfc, outf);
}

// Round 6
// 928.628 us; speedup vs baseline: 4.0870x; 1.1129x over previous
//
#include <hip/hip_runtime.h>

// LSTM decoder: B=256, H=512, L=2, T=64, O=7
// Persistent kernel, round 6:
//  - h-streams stored per-timestep (fresh addresses every phase) => consumer
//    loads are PLAIN CACHED (L2-shared within XCD), no inv, no staleness.
//  - producers write h via sc0sc1 (write-through to IC, no dirty L2 lines).
//  - XCD pinning: m-group = (wg&7)>>1 so each XCD serves one 64-row m-tile.
//  - flags: 8 sub-counters per (phase,m) 128B apart; signal = relaxed agent
//    fetch_add (8 WGs/counter); poll = system-scope relaxed loads (no RMW).
//  - weights in regs/AGPRs (loaded once), c-state in VGPRs for all 64 steps.

#define TT 64
#define NO 7

typedef _Float16 h16;
typedef __attribute__((ext_vector_type(8))) _Float16 half8;
typedef __attribute__((ext_vector_type(4))) float f32x4;
typedef __attribute__((ext_vector_type(4))) int i32x4;

__device__ __forceinline__ float sigf(float x)   { return 1.f / (1.f + __expf(-x)); }
__device__ __forceinline__ float tanhf_(float x) { return 1.f - 2.f / (__expf(2.f * x) + 1.f); }

// ---------------- prologue: pack [W_ih | W_hh] -> f16 Wc[l][n][k], k-major ----
__global__ __launch_bounds__(256) void prep_weights(
    const float* __restrict__ Wih, const float* __restrict__ Whh,
    h16* __restrict__ Wc)
{
    size_t gid = (size_t)blockIdx.x * 256 + threadIdx.x;
    size_t base = gid * 8;
    int l = (int)(base >> 21);
    int rem = (int)(base & ((1u << 21) - 1));
    int n = rem >> 10;
    int k = rem & 1023;
    const float* src = (k < 512)
        ? (Wih + ((size_t)l * 2048 + n) * 512 + k)
        : (Whh + ((size_t)l * 2048 + n) * 512 + (k - 512));
    const float4* s4 = (const float4*)src;
    float4 a = s4[0];
    float4 b = s4[1];
    half8 o;
    o[0] = (h16)a.x; o[1] = (h16)a.y; o[2] = (h16)a.z; o[3] = (h16)a.w;
    o[4] = (h16)b.x; o[5] = (h16)b.y; o[6] = (h16)b.z; o[7] = (h16)b.w;
    *(half8*)(Wc + base) = o;
}

// ---------------- prologue: init Xinit/H0init/H1init + bias ------------------
__global__ __launch_bounds__(256) void init_misc(
    const float* __restrict__ x, const float* __restrict__ h0,
    const float* __restrict__ bih, const float* __restrict__ bhh,
    h16* __restrict__ Xinit, h16* __restrict__ H0init, h16* __restrict__ H1init,
    float* __restrict__ bias)
{
    int i = blockIdx.x * 256 + threadIdx.x;
    if (i < 131072) { Xinit[i]  = (h16)x[i];           return; }
    i -= 131072;
    if (i < 131072) { H0init[i] = (h16)h0[i];          return; }
    i -= 131072;
    if (i < 131072) { H1init[i] = (h16)h0[131072 + i]; return; }
    i -= 131072;
    if (i < 4096) bias[i] = bih[i] + bhh[i];
}

// ---------------- persistent LSTM ------------------------------------------
// 256 WGs x 256 thr, 1 WG/CU. XCD-pinned: m = (wg&7)>>1, us = (wg>>3)+(wg&1)*32.
// WG: 64-row m-tile x 8 h-units. Wave w: rows (w>>1)*32..+32, units (w&1)*4..+4
// (16 gate-cols, col = 4*ulocal + gate).
__global__ __launch_bounds__(256, 1) void lstm_persist(
    const h16* __restrict__ Wc, const float* __restrict__ bias,
    const float* __restrict__ c0in,
    const h16* __restrict__ Xinit, const h16* __restrict__ H0init,
    const h16* __restrict__ H1init,
    h16* __restrict__ H0, h16* __restrict__ H1,
    float* __restrict__ h_st, float* __restrict__ c_st,
    unsigned* __restrict__ flags)
{
    __shared__ char ldsraw[65536];   // 2 x 32KB A-chunk double buffer

    const int wg   = blockIdx.x;
    const int m    = (wg & 7) >> 1;               // XCD-pinned m-group
    const int us   = (wg >> 3) + (wg & 1) * 32;   // unit slice 0..63
    const int myoct = us >> 3;
    const int tid  = threadIdx.x, w = tid >> 6, lane = tid & 63;
    const int u0   = us * 8;
    const int m0   = m * 64;
    const int rowbase = m0 + (w >> 1) * 32;
    const int ubase   = u0 + (w & 1) * 4;
    const int mcol = lane & 15, kq = lane >> 4;
    const int nrow = (mcol & 3) * 512 + ubase + (mcol >> 2);
    const int lrow = (w >> 1) * 32 + mcol;     // local row of m-subtile 0
    const int sw   = mcol & 7;                 // LDS XOR swizzle key

    // ---- B fragments for both layers -> registers/AGPRs (loaded once) ----
    half8 Bw0[32], Bw1[32];
#pragma unroll
    for (int ks = 0; ks < 32; ++ks) {
        Bw0[ks] = *(const half8*)(Wc + (size_t)nrow * 1024 + ks * 32 + kq * 8);
        Bw1[ks] = *(const half8*)(Wc + (size_t)(2048 + nrow) * 1024 + ks * 32 + kq * 8);
    }

    // ---- epilogue lane mapping (round-2/5 verified) ----
    const int eunit = ubase + (lane & 3);
    const int erow0 = rowbase + (lane >> 2);   // m-subtile 0; +16 for subtile 1
    float4 bz0 = make_float4(bias[eunit], bias[512 + eunit],
                             bias[1024 + eunit], bias[1536 + eunit]);
    float4 bz1 = make_float4(bias[2048 + eunit], bias[2048 + 512 + eunit],
                             bias[2048 + 1024 + eunit], bias[2048 + 1536 + eunit]);

    float creg[2][2], hreg[2][2];
#pragma unroll
    for (int mt = 0; mt < 2; ++mt) {
        creg[0][mt] = c0in[(erow0 + mt * 16) * 512 + eunit];
        creg[1][mt] = c0in[131072 + (erow0 + mt * 16) * 512 + eunit];
        hreg[0][mt] = 0.f; hreg[1][mt] = 0.f;
    }

// plain CACHED 16B loads of k-half `cs` (0/1) of 64-row tile from BASE (bytes,
// row stride 1024B). Fresh addresses each phase => L2 can never be stale.
#define ISSUE_CHUNK(BASE, cs) do {                                            \
    _Pragma("unroll")                                                         \
    for (int j = 0; j < 8; ++j) {                                             \
        int g = j * 256 + tid;                                                \
        int voff = (g >> 5) * 1024 + (cs) * 512 + (g & 31) * 16;              \
        asm volatile("global_load_dwordx4 %0, %1, %2"                         \
            : "=v"(tmp[j]) : "v"(voff), "s"(BASE) : "memory");                \
    } } while (0)

// drain oldest-first into LDS buffer `par` with XOR swizzle
#define WRITE_CHUNK(par) do {                                                 \
    _Pragma("unroll")                                                         \
    for (int j = 0; j < 8; ++j) {                                             \
        asm volatile("s_waitcnt vmcnt(%0)" :: "i"(7 - j) : "memory");         \
        int g = j * 256 + tid;                                                \
        int row = g >> 5, bc = g & 31;                                        \
        *(i32x4*)(ldsraw + (par) * 32768 + row * 512 +                        \
                  ((bc ^ (row & 7)) * 16)) = tmp[j];                          \
    } } while (0)

#define PHASE(PH, WAIT, XSRC, HSRC, BW, BZ, CREG, HREG, HDST) do {            \
    if ((WAIT) && tid == 0) {                                                 \
        unsigned* fb = flags + (((PH) - 1) * 4 + m) * 256;                    \
        for (;;) {                                                            \
            unsigned s = 0;                                                   \
            _Pragma("unroll")                                                 \
            for (int o = 0; o < 8; ++o)                                       \
                s += __hip_atomic_load(fb + o * 32, __ATOMIC_RELAXED,         \
                                       __HIP_MEMORY_SCOPE_SYSTEM);            \
            if (s == 64u) break;                                              \
            __builtin_amdgcn_s_sleep(1);                                      \
        }                                                                     \
    }                                                                         \
    __syncthreads();                                                          \
    const char* bx = (const char*)(XSRC) + (size_t)m0 * 1024;                 \
    const char* bh = (const char*)(HSRC) + (size_t)m0 * 1024;                 \
    i32x4 tmp[8];                                                             \
    ISSUE_CHUNK(bx, 0);                                                       \
    WRITE_CHUNK(0);                                                           \
    f32x4 acc0 = {0.f,0.f,0.f,0.f}, acc1 = {0.f,0.f,0.f,0.f};                 \
    _Pragma("unroll")                                                         \
    for (int ch = 0; ch < 4; ++ch) {                                          \
        __syncthreads();                                                      \
        if (ch == 0) ISSUE_CHUNK(bx, 1);                                      \
        else if (ch == 1) ISSUE_CHUNK(bh, 0);                                 \
        else if (ch == 2) ISSUE_CHUNK(bh, 1);                                 \
        const int par = ch & 1;                                               \
        _Pragma("unroll")                                                     \
        for (int ks = 0; ks < 8; ++ks) {                                      \
            half8 a0 = *(const half8*)(ldsraw + par * 32768 + lrow * 512 +    \
                          (((kq + 4 * ks) ^ sw) * 16));                       \
            half8 a1 = *(const half8*)(ldsraw + par * 32768 +                 \
                          (lrow + 16) * 512 + (((kq + 4 * ks) ^ sw) * 16));   \
            acc0 = __builtin_amdgcn_mfma_f32_16x16x32_f16(a0, (BW)[ch*8+ks],  \
                                                          acc0, 0, 0, 0);     \
            acc1 = __builtin_amdgcn_mfma_f32_16x16x32_f16(a1, (BW)[ch*8+ks],  \
                                                          acc1, 0, 0, 0);     \
        }                                                                     \
        if (ch < 3) WRITE_CHUNK(par ^ 1);                                     \
    }                                                                         \
    __syncthreads();                                                          \
    float* scrw = (float*)(ldsraw + w * 1024);  /* 16x16 f32, per wave */     \
    _Pragma("unroll")                                                         \
    for (int mt = 0; mt < 2; ++mt) {                                          \
        f32x4 accv = mt ? acc1 : acc0;                                        \
        _Pragma("unroll")                                                     \
        for (int rr = 0; rr < 4; ++rr)                                        \
            scrw[(kq * 4 + rr) * 16 + mcol] = accv[rr];                       \
        float4 g4 = *(const float4*)&scrw[(lane >> 2) * 16 + (lane & 3) * 4]; \
        float iv = sigf(g4.x + (BZ).x);                                       \
        float fv = sigf(g4.y + (BZ).y);                                       \
        float gv = tanhf_(g4.z + (BZ).z);                                     \
        float ov = sigf(g4.w + (BZ).w);                                       \
        float cc = fv * (CREG)[mt] + iv * gv;                                 \
        float hh = ov * tanhf_(cc);                                           \
        (CREG)[mt] = cc; (HREG)[mt] = hh;                                     \
        h16 hv = (h16)hh;                                                     \
        unsigned hb = (unsigned)__builtin_bit_cast(unsigned short, hv);       \
        int vx = ((erow0 + mt * 16) * 512 + eunit) * 2;                       \
        asm volatile("global_store_short %0, %1, %2 sc0 sc1"                  \
            :: "v"(vx), "v"(hb), "s"(HDST) : "memory");                       \
    }                                                                         \
    asm volatile("s_waitcnt vmcnt(0)" ::: "memory");                          \
    __syncthreads();                                                          \
    if (tid == 0)                                                             \
        __hip_atomic_fetch_add(flags + (((PH) * 4 + m) * 8 + myoct) * 32, 1u, \
                               __ATOMIC_RELAXED, __HIP_MEMORY_SCOPE_AGENT);   \
} while (0)

#pragma unroll 1
    for (int t = 0; t < TT; ++t) {
        const h16* x0src = t ? (H1 + (size_t)(t - 1) * 131072) : Xinit;
        const h16* h0src = t ? (H0 + (size_t)(t - 1) * 131072) : H0init;
        // layer 0 (phase 2t): A = [x0src | h0src] -> H0[t]
        PHASE(2 * t, t > 0, x0src, h0src, Bw0, bz0, creg[0], hreg[0],
              (H0 + (size_t)t * 131072));
        const h16* h1src = t ? (H1 + (size_t)(t - 1) * 131072) : H1init;
        // layer 1 (phase 2t+1): A = [H0[t] | h1src] -> H1[t]
        PHASE(2 * t + 1, 1, (H0 + (size_t)t * 131072), h1src, Bw1, bz1,
              creg[1], hreg[1], (H1 + (size_t)t * 131072));
    }

    // ---- final hT / cT (normal stores; kernel-end release flushes) ----
#pragma unroll
    for (int mt = 0; mt < 2; ++mt) {
        int idx = (erow0 + mt * 16) * 512 + eunit;
        h_st[idx]          = hreg[0][mt];
        h_st[131072 + idx] = hreg[1][mt];
        c_st[idx]          = creg[0][mt];
        c_st[131072 + idx] = creg[1][mt];
    }
}

// ---------------- final FC over all stored h1(t): (T*B) x 7, K=512 -----------
__global__ __launch_bounds__(256) void fc_kernel(
    const h16* __restrict__ H1, const float* __restrict__ Wfc,
    const float* __restrict__ bfc, float* __restrict__ out)
{
    __shared__ float wl[NO * 512];
    for (int i = threadIdx.x; i < NO * 512; i += 256) wl[i] = Wfc[i];
    __syncthreads();
    const int wave = threadIdx.x >> 6, lane = threadIdx.x & 63;
    const int row = blockIdx.x * 4 + wave;   // row = t*256 + b
    const h16* hr = H1 + (size_t)row * 512;
    float acc[NO] = {0, 0, 0, 0, 0, 0, 0};
#pragma unroll
    for (int i = 0; i < 8; ++i) {
        float hv = (float)hr[i * 64 + lane];
#pragma unroll
        for (int o = 0; o < NO; ++o) acc[o] += hv * wl[o * 512 + i * 64 + lane];
    }
#pragma unroll
    for (int o = 0; o < NO; ++o)
#pragma unroll
        for (int off = 32; off; off >>= 1) acc[o] += __shfl_down(acc[o], off);
    if (lane == 0) {
        const int t = row >> 8, b = row & 255;
#pragma unroll
        for (int o = 0; o < NO; ++o) out[b * (TT * NO) + t * NO + o] = acc[o] + bfc[o];
    }
}

extern "C" void kernel_launch(void* const* d_in, const int* in_sizes, int n_in,
                              void* d_out, int out_size, void* d_ws, size_t ws_size,
                              hipStream_t stream)
{
    (void)in_sizes; (void)n_in; (void)out_size; (void)ws_size;
    const float* x   = (const float*)d_in[0];
    const float* h0  = (const float*)d_in[1];
    const float* c0  = (const float*)d_in[2];
    const float* Wih = (const float*)d_in[3];
    const float* Whh = (const float*)d_in[4];
    const float* bih = (const float*)d_in[5];
    const float* bhh = (const float*)d_in[6];
    const float* Wfc = (const float*)d_in[7];
    const float* bfc = (const float*)d_in[8];

    float* outf = (float*)d_out;                 // decoded (256*64*7)
    float* h_st = outf + 114688;                 // hT (2,256,512)
    float* c_st = h_st + 262144;                 // cT (2,256,512)

    char* ws = (char*)d_ws;
    h16*      Wc     = (h16*)ws;                         // 8 MB
    float*    bias   = (float*)(ws + 8388608);           // 16 KB
    h16*      Xinit  = (h16*)(ws + 8404992);             // 256 KB
    h16*      H0init = (h16*)(ws + 8667136);             // 256 KB
    h16*      H1init = (h16*)(ws + 8929280);             // 256 KB
    h16*      H0     = (h16*)(ws + 9191424);             // 16 MB (64 steps)
    h16*      H1     = (h16*)(ws + 25968640);            // 16 MB (64 steps)
    unsigned* flags  = (unsigned*)(ws + 42745856);       // 512 KB

    prep_weights<<<2048, 256, 0, stream>>>(Wih, Whh, Wc);
    init_misc<<<1552, 256, 0, stream>>>(x, h0, bih, bhh, Xinit, H0init, H1init, bias);
    hipMemsetAsync(flags, 0, 524288, stream);
    lstm_persist<<<256, 256, 0, stream>>>(Wc, bias, c0, Xinit, H0init, H1init,
                                          H0, H1, h_st, c_st, flags);
    fc_kernel<<<4096, 256, 0, stream>>>(H1, Wfc, bfc, outf);
}

// Round 7
// 825.522 us; speedup vs baseline: 4.5975x; 1.1249x over previous
//
#include <hip/hip_runtime.h>

// LSTM decoder: B=256, H=512, L=2, T=64, O=7
// Persistent kernel, round 7:
//  - h-streams per-timestep (fresh addresses) => consumer loads PLAIN CACHED.
//  - producer h-stores now COALESCED 16B dwordx4 sc0sc1 (via LDS gather) —
//    kills the 4x partial-sector write amplification seen in round 6.
//  - h-part of A (complete one phase earlier) prefetched BEFORE the flag
//    poll; only the fresh x-part is latency-exposed after the poll.
//  - flags: 8 sub-counters per (phase,m) 128B apart; signal = relaxed agent
//    fetch_add; poll = system-scope relaxed loads.
//  - weights in regs/AGPRs (loaded once), c-state in VGPRs for all 64 steps.

#define TT 64
#define NO 7

typedef _Float16 h16;
typedef __attribute__((ext_vector_type(8))) _Float16 half8;
typedef __attribute__((ext_vector_type(4))) float f32x4;
typedef __attribute__((ext_vector_type(4))) int i32x4;

__device__ __forceinline__ float sigf(float x)   { return 1.f / (1.f + __expf(-x)); }
__device__ __forceinline__ float tanhf_(float x) { return 1.f - 2.f / (__expf(2.f * x) + 1.f); }

// ---------------- prologue: pack [W_ih | W_hh] -> f16 Wc[l][n][k], k-major ----
__global__ __launch_bounds__(256) void prep_weights(
    const float* __restrict__ Wih, const float* __restrict__ Whh,
    h16* __restrict__ Wc)
{
    size_t gid = (size_t)blockIdx.x * 256 + threadIdx.x;
    size_t base = gid * 8;
    int l = (int)(base >> 21);
    int rem = (int)(base & ((1u << 21) - 1));
    int n = rem >> 10;
    int k = rem & 1023;
    const float* src = (k < 512)
        ? (Wih + ((size_t)l * 2048 + n) * 512 + k)
        : (Whh + ((size_t)l * 2048 + n) * 512 + (k - 512));
    const float4* s4 = (const float4*)src;
    float4 a = s4[0];
    float4 b = s4[1];
    half8 o;
    o[0] = (h16)a.x; o[1] = (h16)a.y; o[2] = (h16)a.z; o[3] = (h16)a.w;
    o[4] = (h16)b.x; o[5] = (h16)b.y; o[6] = (h16)b.z; o[7] = (h16)b.w;
    *(half8*)(Wc + base) = o;
}

// ---------------- prologue: init Xinit/H0init/H1init + bias ------------------
__global__ __launch_bounds__(256) void init_misc(
    const float* __restrict__ x, const float* __restrict__ h0,
    const float* __restrict__ bih, const float* __restrict__ bhh,
    h16* __restrict__ Xinit, h16* __restrict__ H0init, h16* __restrict__ H1init,
    float* __restrict__ bias)
{
    int i = blockIdx.x * 256 + threadIdx.x;
    if (i < 131072) { Xinit[i]  = (h16)x[i];           return; }
    i -= 131072;
    if (i < 131072) { H0init[i] = (h16)h0[i];          return; }
    i -= 131072;
    if (i < 131072) { H1init[i] = (h16)h0[131072 + i]; return; }
    i -= 131072;
    if (i < 4096) bias[i] = bih[i] + bhh[i];
}

// ---------------- persistent LSTM ------------------------------------------
// 256 WGs x 256 thr, 1 WG/CU. XCD-pinned: m = (wg&7)>>1, us = (wg>>3)+(wg&1)*32.
// WG: 64-row m-tile x 8 h-units. Wave w: rows (w>>1)*32..+32, units (w&1)*4..+4
// (16 gate-cols, col = 4*ulocal + gate).
__global__ __launch_bounds__(256, 1) void lstm_persist(
    const h16* __restrict__ Wc, const float* __restrict__ bias,
    const float* __restrict__ c0in,
    const h16* __restrict__ Xinit, const h16* __restrict__ H0init,
    const h16* __restrict__ H1init,
    h16* __restrict__ H0, h16* __restrict__ H1,
    float* __restrict__ h_st, float* __restrict__ c_st,
    unsigned* __restrict__ flags)
{
    __shared__ char ldsraw[65536];   // 2 x 32KB A-chunk double buffer

    const int wg   = blockIdx.x;
    const int m    = (wg & 7) >> 1;               // XCD-pinned m-group
    const int us   = (wg >> 3) + (wg & 1) * 32;   // unit slice 0..63
    const int myoct = us >> 3;
    const int tid  = threadIdx.x, w = tid >> 6, lane = tid & 63;
    const int u0   = us * 8;
    const int m0   = m * 64;
    const int rowbase = m0 + (w >> 1) * 32;
    const int ubase   = u0 + (w & 1) * 4;
    const int mcol = lane & 15, kq = lane >> 4;
    const int nrow = (mcol & 3) * 512 + ubase + (mcol >> 2);
    const int lrow = (w >> 1) * 32 + mcol;     // local row of m-subtile 0
    const int sw   = mcol & 7;                 // LDS XOR swizzle key
    const int lrloc = (w >> 1) * 32 + (lane >> 2);   // epilogue local row
    const int luloc = (w & 1) * 4 + (lane & 3);      // epilogue local unit

    // ---- B fragments for both layers -> registers/AGPRs (loaded once) ----
    half8 Bw0[32], Bw1[32];
#pragma unroll
    for (int ks = 0; ks < 32; ++ks) {
        Bw0[ks] = *(const half8*)(Wc + (size_t)nrow * 1024 + ks * 32 + kq * 8);
        Bw1[ks] = *(const half8*)(Wc + (size_t)(2048 + nrow) * 1024 + ks * 32 + kq * 8);
    }

    // ---- epilogue lane mapping (round-2/5/6 verified) ----
    const int eunit = ubase + (lane & 3);
    const int erow0 = rowbase + (lane >> 2);   // m-subtile 0; +16 for subtile 1
    float4 bz0 = make_float4(bias[eunit], bias[512 + eunit],
                             bias[1024 + eunit], bias[1536 + eunit]);
    float4 bz1 = make_float4(bias[2048 + eunit], bias[2048 + 512 + eunit],
                             bias[2048 + 1024 + eunit], bias[2048 + 1536 + eunit]);

    float creg[2][2], hreg[2][2];
#pragma unroll
    for (int mt = 0; mt < 2; ++mt) {
        creg[0][mt] = c0in[(erow0 + mt * 16) * 512 + eunit];
        creg[1][mt] = c0in[131072 + (erow0 + mt * 16) * 512 + eunit];
        hreg[0][mt] = 0.f; hreg[1][mt] = 0.f;
    }

// plain CACHED 16B loads of k-half `cs` (0/1) of the 64-row tile at BASE
// (row stride 1024B) into tmp[TB..TB+7]. Issue order defines vmcnt drains.
#define ISSUE_CHUNK(BASE, cs, TB) do {                                        \
    _Pragma("unroll")                                                         \
    for (int j = 0; j < 8; ++j) {                                             \
        int g = j * 256 + tid;                                                \
        int voff = (g >> 5) * 1024 + (cs) * 512 + (g & 31) * 16;              \
        asm volatile("global_load_dwordx4 %0, %1, %2"                         \
            : "=v"(tmp[(TB) + j]) : "v"(voff), "s"(BASE) : "memory");         \
    } } while (0)

// drain 8 loads (oldest-first) into LDS buffer `par` with XOR swizzle.
// NB = (outstanding when entering) - 1.
#define WRITE_CHUNK(par, TB, NB) do {                                         \
    _Pragma("unroll")                                                         \
    for (int j = 0; j < 8; ++j) {                                             \
        asm volatile("s_waitcnt vmcnt(%0)" :: "i"((NB) - j) : "memory");      \
        int g = j * 256 + tid;                                                \
        int row = g >> 5, bc = g & 31;                                        \
        *(i32x4*)(ldsraw + (par) * 32768 + row * 512 +                        \
                  ((bc ^ (row & 7)) * 16)) = tmp[(TB) + j];                   \
    } } while (0)

// 8 k-steps of MFMA from LDS buffer `par` against B fragments BW[CO..CO+7]
#define MFMA_CHUNK(par, CO, BW) do {                                          \
    _Pragma("unroll")                                                         \
    for (int ks = 0; ks < 8; ++ks) {                                          \
        half8 a0 = *(const half8*)(ldsraw + (par) * 32768 + lrow * 512 +      \
                      (((kq + 4 * ks) ^ sw) * 16));                           \
        half8 a1 = *(const half8*)(ldsraw + (par) * 32768 +                   \
                      (lrow + 16) * 512 + (((kq + 4 * ks) ^ sw) * 16));       \
        acc0 = __builtin_amdgcn_mfma_f32_16x16x32_f16(a0, (BW)[(CO) + ks],    \
                                                      acc0, 0, 0, 0);         \
        acc1 = __builtin_amdgcn_mfma_f32_16x16x32_f16(a1, (BW)[(CO) + ks],    \
                                                      acc1, 0, 0, 0);         \
    } } while (0)

// chunk order: h0 (k512-767, BW[16..23]), h1 (k768-1023, BW[24..31]),
//              x0 (k0-255,   BW[0..7]),   x1 (k256-511,  BW[8..15])
// h-chunks prefetched BEFORE the poll (their producer flag was polled one
// phase earlier => data complete; addresses write-once => caches never stale).
#define PHASE(PH, WAIT, XSRC, HSRC, BW, BZ, CREG, HREG, HDST) do {            \
    const char* bx = (const char*)(XSRC) + (size_t)m0 * 1024;                 \
    const char* bh = (const char*)(HSRC) + (size_t)m0 * 1024;                 \
    i32x4 tmp[16];                                                            \
    ISSUE_CHUNK(bh, 0, 0);                                                    \
    ISSUE_CHUNK(bh, 1, 8);                                                    \
    if ((WAIT) && tid == 0) {                                                 \
        unsigned* fb = flags + (((PH) - 1) * 4 + m) * 256;                    \
        for (;;) {                                                            \
            unsigned s = 0;                                                   \
            _Pragma("unroll")                                                 \
            for (int o = 0; o < 8; ++o)                                       \
                s += __hip_atomic_load(fb + o * 32, __ATOMIC_RELAXED,         \
                                       __HIP_MEMORY_SCOPE_SYSTEM);            \
            if (s == 64u) break;                                              \
            __builtin_amdgcn_s_sleep(1);                                      \
        }                                                                     \
    }                                                                         \
    __syncthreads();                                                          \
    f32x4 acc0 = {0.f,0.f,0.f,0.f}, acc1 = {0.f,0.f,0.f,0.f};                 \
    WRITE_CHUNK(0, 0, 15);                                                    \
    __syncthreads();                                                          \
    ISSUE_CHUNK(bx, 0, 0);                                                    \
    MFMA_CHUNK(0, 16, BW);                                                    \
    WRITE_CHUNK(1, 8, 15);                                                    \
    __syncthreads();                                                          \
    ISSUE_CHUNK(bx, 1, 8);                                                    \
    MFMA_CHUNK(1, 24, BW);                                                    \
    WRITE_CHUNK(0, 0, 15);                                                    \
    __syncthreads();                                                          \
    MFMA_CHUNK(0, 0, BW);                                                     \
    WRITE_CHUNK(1, 8, 7);                                                     \
    __syncthreads();                                                          \
    MFMA_CHUNK(1, 8, BW);                                                     \
    /* ---- epilogue: transpose, cell, LDS-gather, coalesced 16B flush ---- */ \
    float* scrw = (float*)(ldsraw + w * 1024);                                \
    h16* hbuf = (h16*)(ldsraw + 8192);                                        \
    _Pragma("unroll")                                                         \
    for (int mt = 0; mt < 2; ++mt) {                                          \
        f32x4 accv = mt ? acc1 : acc0;                                        \
        _Pragma("unroll")                                                     \
        for (int rr = 0; rr < 4; ++rr)                                        \
            scrw[(kq * 4 + rr) * 16 + mcol] = accv[rr];                       \
        float4 g4 = *(const float4*)&scrw[(lane >> 2) * 16 + (lane & 3) * 4]; \
        float iv = sigf(g4.x + (BZ).x);                                       \
        float fv = sigf(g4.y + (BZ).y);                                       \
        float gv = tanhf_(g4.z + (BZ).z);                                     \
        float ov = sigf(g4.w + (BZ).w);                                       \
        float cc = fv * (CREG)[mt] + iv * gv;                                 \
        float hh = ov * tanhf_(cc);                                           \
        (CREG)[mt] = cc; (HREG)[mt] = hh;                                     \
        hbuf[(lrloc + mt * 16) * 8 + luloc] = (h16)hh;                        \
    }                                                                         \
    __syncthreads();                                                          \
    if (tid < 64) {                                                           \
        i32x4 hv16 = *(const i32x4*)(ldsraw + 8192 + tid * 16);               \
        int voff = (m0 + tid) * 1024 + u0 * 2;                                \
        asm volatile("global_store_dwordx4 %0, %1, %2 sc0 sc1"                \
            :: "v"(voff), "v"(hv16), "s"(HDST) : "memory");                   \
    }                                                                         \
    asm volatile("s_waitcnt vmcnt(0)" ::: "memory");                          \
    __syncthreads();                                                          \
    if (tid == 0)                                                             \
        __hip_atomic_fetch_add(flags + (((PH) * 4 + m) * 8 + myoct) * 32, 1u, \
                               __ATOMIC_RELAXED, __HIP_MEMORY_SCOPE_AGENT);   \
} while (0)

#pragma unroll 1
    for (int t = 0; t < TT; ++t) {
        const h16* x0src = t ? (H1 + (size_t)(t - 1) * 131072) : Xinit;
        const h16* h0src = t ? (H0 + (size_t)(t - 1) * 131072) : H0init;
        // layer 0 (phase 2t): A = [x0src | h0src] -> H0[t]
        PHASE(2 * t, t > 0, x0src, h0src, Bw0, bz0, creg[0], hreg[0],
              (H0 + (size_t)t * 131072));
        const h16* h1src = t ? (H1 + (size_t)(t - 1) * 131072) : H1init;
        // layer 1 (phase 2t+1): A = [H0[t] | h1src] -> H1[t]
        PHASE(2 * t + 1, 1, (H0 + (size_t)t * 131072), h1src, Bw1, bz1,
              creg[1], hreg[1], (H1 + (size_t)t * 131072));
    }

    // ---- final hT / cT (normal stores; kernel-end release flushes) ----
#pragma unroll
    for (int mt = 0; mt < 2; ++mt) {
        int idx = (erow0 + mt * 16) * 512 + eunit;
        h_st[idx]          = hreg[0][mt];
        h_st[131072 + idx] = hreg[1][mt];
        c_st[idx]          = creg[0][mt];
        c_st[131072 + idx] = creg[1][mt];
    }
}

// ---------------- final FC over all stored h1(t): (T*B) x 7, K=512 -----------
__global__ __launch_bounds__(256) void fc_kernel(
    const h16* __restrict__ H1, const float* __restrict__ Wfc,
    const float* __restrict__ bfc, float* __restrict__ out)
{
    __shared__ float wl[NO * 512];
    for (int i = threadIdx.x; i < NO * 512; i += 256) wl[i] = Wfc[i];
    __syncthreads();
    const int wave = threadIdx.x >> 6, lane = threadIdx.x & 63;
    const int row = blockIdx.x * 4 + wave;   // row = t*256 + b
    const h16* hr = H1 + (size_t)row * 512;
    float acc[NO] = {0, 0, 0, 0, 0, 0, 0};
#pragma unroll
    for (int i = 0; i < 8; ++i) {
        float hv = (float)hr[i * 64 + lane];
#pragma unroll
        for (int o = 0; o < NO; ++o) acc[o] += hv * wl[o * 512 + i * 64 + lane];
    }
#pragma unroll
    for (int o = 0; o < NO; ++o)
#pragma unroll
        for (int off = 32; off; off >>= 1) acc[o] += __shfl_down(acc[o], off);
    if (lane == 0) {
        const int t = row >> 8, b = row & 255;
#pragma unroll
        for (int o = 0; o < NO; ++o) out[b * (TT * NO) + t * NO + o] = acc[o] + bfc[o];
    }
}

extern "C" void kernel_launch(void* const* d_in, const int* in_sizes, int n_in,
                              void* d_out, int out_size, void* d_ws, size_t ws_size,
                              hipStream_t stream)
{
    (void)in_sizes; (void)n_in; (void)out_size; (void)ws_size;
    const float* x   = (const float*)d_in[0];
    const float* h0  = (const float*)d_in[1];
    const float* c0  = (const float*)d_in[2];
    const float* Wih = (const float*)d_in[3];
    const float* Whh = (const float*)d_in[4];
    const float* bih = (const float*)d_in[5];
    const float* bhh = (const float*)d_in[6];
    const float* Wfc = (const float*)d_in[7];
    const float* bfc = (const float*)d_in[8];

    float* outf = (float*)d_out;                 // decoded (256*64*7)
    float* h_st = outf + 114688;                 // hT (2,256,512)
    float* c_st = h_st + 262144;                 // cT (2,256,512)

    char* ws = (char*)d_ws;
    h16*      Wc     = (h16*)ws;                         // 8 MB
    float*    bias   = (float*)(ws + 8388608);           // 16 KB
    h16*      Xinit  = (h16*)(ws + 8404992);             // 256 KB
    h16*      H0init = (h16*)(ws + 8667136);             // 256 KB
    h16*      H1init = (h16*)(ws + 8929280);             // 256 KB
    h16*      H0     = (h16*)(ws + 9191424);             // 16 MB (64 steps)
    h16*      H1     = (h16*)(ws + 25968640);            // 16 MB (64 steps)
    unsigned* flags  = (unsigned*)(ws + 42745856);       // 512 KB

    prep_weights<<<2048, 256, 0, stream>>>(Wih, Whh, Wc);
    init_misc<<<1552, 256, 0, stream>>>(x, h0, bih, bhh, Xinit, H0init, H1init, bias);
    hipMemsetAsync(flags, 0, 524288, stream);
    lstm_persist<<<256, 256, 0, stream>>>(Wc, bias, c0, Xinit, H0init, H1init,
                                          H0, H1, h_st, c_st, flags);
    fc_kernel<<<4096, 256, 0, stream>>>(H1, Wfc, bfc, outf);
}